// Round 1
// baseline (1134.308 us; speedup 1.0000x reference)
//
#include <hip/hip_runtime.h>
#include <hip/hip_bf16.h>
#include <math.h>

#define C128 128
#define OUT_CH 10

// ---------------- CSR build ----------------

__global__ void hist_kernel(const int* __restrict__ ei, int* __restrict__ deg, int E) {
    int e = blockIdx.x * blockDim.x + threadIdx.x;
    if (e < E) atomicAdd(&deg[ei[E + e]], 1);
}

__global__ __launch_bounds__(1024) void scan_kernel(const int* __restrict__ deg,
                                                    int* __restrict__ row_ptr, int N) {
    __shared__ int sums[1024];
    int t = threadIdx.x;
    int C = (N + 1023) >> 10;
    int begin = t * C;
    int end = begin + C; if (end > N) end = N;
    int s = 0;
    for (int i = begin; i < end; ++i) s += deg[i];
    sums[t] = s;
    __syncthreads();
    for (int off = 1; off < 1024; off <<= 1) {
        int v = (t >= off) ? sums[t - off] : 0;
        __syncthreads();
        sums[t] += v;
        __syncthreads();
    }
    int run = (t == 0) ? 0 : sums[t - 1];
    for (int i = begin; i < end; ++i) { int d = deg[i]; row_ptr[i] = run; run += d; }
    if (t == 1023) row_ptr[N] = run;
}

__global__ void copy_int(const int* __restrict__ a, int* __restrict__ b, int n) {
    int i = blockIdx.x * blockDim.x + threadIdx.x;
    if (i < n) b[i] = a[i];
}

__global__ void fill_kernel(const int* __restrict__ ei, const float* __restrict__ ew,
                            int* __restrict__ cursor, int* __restrict__ csr_src,
                            float* __restrict__ csr_w, int E) {
    int e = blockIdx.x * blockDim.x + threadIdx.x;
    if (e < E) {
        int dst = ei[E + e];
        int pos = atomicAdd(&cursor[dst], 1);
        csr_src[pos] = ei[e];
        csr_w[pos] = ew[e];
    }
}

// ---------------- aggregation: one wave per node, atomic-free ----------------

__global__ __launch_bounds__(256) void gather_kernel(
    const float* __restrict__ x, const int* __restrict__ row_ptr,
    const int* __restrict__ csr_src, const float* __restrict__ csr_w,
    float* __restrict__ agg, int N)
{
    int node = blockIdx.x * 4 + (threadIdx.x >> 6);
    int lane = threadIdx.x & 63;
    if (node >= N) return;
    int i = row_ptr[node];
    int e1 = row_ptr[node + 1];
    float2 acc = make_float2(0.f, 0.f);
    int   sN = 0; float wN = 0.f;
    if (i < e1) { sN = csr_src[i]; wN = csr_w[i]; }
    while (i < e1) {
        int s = sN; float w = wN;
        int j = i + 1;
        if (j < e1) { sN = csr_src[j]; wN = csr_w[j]; }
        float2 v = *(const float2*)&x[(size_t)s * C128 + lane * 2];
        acc.x += v.x * w;
        acc.y += v.y * w;
        i = j;
    }
    *(float2*)&agg[(size_t)node * C128 + lane * 2] = acc;
}

// ---------------- fused dual GEMM + bias + relu ----------------
// out[n][c] = relu( sum_k A[n][k]*Wr[k][c] + X[n][k]*Wt[k][c] + bias[c] )
// 64-node x 128-ch tile, 256 threads, 8 nodes x 4 ch per thread, K chunked by 32.

__global__ __launch_bounds__(256) void gemm_dual(
    const float* __restrict__ A, const float* __restrict__ X,
    const float* __restrict__ Wr, const float* __restrict__ Wt,
    const float* __restrict__ bias, float* __restrict__ out, int N)
{
    __shared__ float Wl[32][128];   // 16 KB
    __shared__ float Il[64][36];    // 9.2 KB, stride 36 breaks bank aliasing
    const int t = threadIdx.x;
    const int node0 = blockIdx.x * 64;
    const int jr = t >> 5;          // 0..7
    const int cg = t & 31;          // float4 column group

    float4 acc[8];
#pragma unroll
    for (int j = 0; j < 8; ++j) acc[j] = make_float4(0.f, 0.f, 0.f, 0.f);

    for (int chunk = 0; chunk < 8; ++chunk) {
        const float* Wsrc = (chunk < 4) ? Wr : Wt;
        const float* Isrc = (chunk < 4) ? A  : X;
        const int k0 = (chunk & 3) * 32;
        __syncthreads();
        // stage W rows k0..k0+31 (32x128 floats)
#pragma unroll
        for (int i = 0; i < 4; ++i) {
            int idx = t + 256 * i;          // 0..1023 float4 slots
            int r = idx >> 5, c = idx & 31;
            *(float4*)&Wl[r][c * 4] = *(const float4*)&Wsrc[(size_t)(k0 + r) * C128 + c * 4];
        }
        // stage input tile (64 nodes x 32 k)
#pragma unroll
        for (int i = 0; i < 2; ++i) {
            int idx = t + 256 * i;          // 0..511 float4 slots
            int r = idx >> 3, c = idx & 7;
            int nn = node0 + r;
            float4 v = make_float4(0.f, 0.f, 0.f, 0.f);
            if (nn < N) v = *(const float4*)&Isrc[(size_t)nn * C128 + k0 + c * 4];
            *(float4*)&Il[r][c * 4] = v;
        }
        __syncthreads();
#pragma unroll
        for (int k = 0; k < 32; k += 4) {
            float4 av[8];
#pragma unroll
            for (int j = 0; j < 8; ++j) av[j] = *(float4*)&Il[jr + 8 * j][k];
#pragma unroll
            for (int kk = 0; kk < 4; ++kk) {
                float4 w = *(float4*)&Wl[k + kk][cg * 4];
#pragma unroll
                for (int j = 0; j < 8; ++j) {
                    float aj = (kk == 0) ? av[j].x : (kk == 1) ? av[j].y
                             : (kk == 2) ? av[j].z : av[j].w;
                    acc[j].x += aj * w.x;
                    acc[j].y += aj * w.y;
                    acc[j].z += aj * w.z;
                    acc[j].w += aj * w.w;
                }
            }
        }
    }

    float4 bv = *(const float4*)&bias[cg * 4];
#pragma unroll
    for (int j = 0; j < 8; ++j) {
        int nn = node0 + jr + 8 * j;
        if (nn < N) {
            float4 f;
            f.x = fmaxf(acc[j].x + bv.x, 0.f);
            f.y = fmaxf(acc[j].y + bv.y, 0.f);
            f.z = fmaxf(acc[j].z + bv.z, 0.f);
            f.w = fmaxf(acc[j].w + bv.w, 0.f);
            *(float4*)&out[(size_t)nn * C128 + cg * 4] = f;
        }
    }
}

// ---------------- head: x3 @ W_lin + b_lin, log_softmax ----------------

__global__ __launch_bounds__(256) void head_kernel(
    const float* __restrict__ x, const float* __restrict__ Wl,
    const float* __restrict__ bl, float* __restrict__ out, int N)
{
    int n = blockIdx.x * blockDim.x + threadIdx.x;
    if (n >= N) return;
    float acc[OUT_CH];
#pragma unroll
    for (int c = 0; c < OUT_CH; ++c) acc[c] = bl[c];
    const float4* row = (const float4*)(x + (size_t)n * C128);
#pragma unroll 4
    for (int kk = 0; kk < 32; ++kk) {
        float4 v = row[kk];
        int k = kk * 4;
#pragma unroll
        for (int c = 0; c < OUT_CH; ++c) {
            acc[c] += v.x * Wl[(k + 0) * OUT_CH + c]
                    + v.y * Wl[(k + 1) * OUT_CH + c]
                    + v.z * Wl[(k + 2) * OUT_CH + c]
                    + v.w * Wl[(k + 3) * OUT_CH + c];
        }
    }
    float m = acc[0];
#pragma unroll
    for (int c = 1; c < OUT_CH; ++c) m = fmaxf(m, acc[c]);
    float s = 0.f;
#pragma unroll
    for (int c = 0; c < OUT_CH; ++c) s += __expf(acc[c] - m);
    float lse = m + __logf(s);
#pragma unroll
    for (int c = 0; c < OUT_CH; ++c) out[(size_t)n * OUT_CH + c] = acc[c] - lse;
}

// ---------------- launch ----------------

extern "C" void kernel_launch(void* const* d_in, const int* in_sizes, int n_in,
                              void* d_out, int out_size, void* d_ws, size_t ws_size,
                              hipStream_t stream) {
    const float* x0   = (const float*)d_in[0];
    const int*   ei   = (const int*)  d_in[1];
    const float* ew   = (const float*)d_in[2];
    const float* W1r  = (const float*)d_in[3];
    const float* b1   = (const float*)d_in[4];
    const float* W1t  = (const float*)d_in[5];
    const float* W2r  = (const float*)d_in[6];
    const float* b2   = (const float*)d_in[7];
    const float* W2t  = (const float*)d_in[8];
    const float* W3r  = (const float*)d_in[9];
    const float* b3   = (const float*)d_in[10];
    const float* W3t  = (const float*)d_in[11];
    const float* Wlin = (const float*)d_in[12];
    const float* blin = (const float*)d_in[13];

    const int N = in_sizes[0] / C128;
    const int E = in_sizes[1] / 2;

    char* ws = (char*)d_ws;
    size_t fbytes = (size_t)N * C128 * sizeof(float);   // 51.2 MB
    float* agg     = (float*)(ws);
    float* buf0    = (float*)(ws + fbytes);
    float* buf1    = (float*)(ws + 2 * fbytes);
    float* csr_w   = (float*)(ws + 3 * fbytes);
    int*   row_ptr = (int*)  (ws + 3 * fbytes + (size_t)E * 4);
    int*   cursor  = row_ptr + (N + 1);                 // doubles as deg histogram
    int*   csr_src = cursor + N;

    // build CSR (dst-indexed), once per call, reused by all 3 layers
    hipMemsetAsync(cursor, 0, (size_t)N * sizeof(int), stream);
    hist_kernel<<<(E + 255) / 256, 256, 0, stream>>>(ei, cursor, E);
    scan_kernel<<<1, 1024, 0, stream>>>(cursor, row_ptr, N);
    copy_int<<<(N + 255) / 256, 256, 0, stream>>>(row_ptr, cursor, N);
    fill_kernel<<<(E + 255) / 256, 256, 0, stream>>>(ei, ew, cursor, csr_src, csr_w, E);

    int gatherGrid = (N + 3) / 4;
    int gemmGrid   = (N + 63) / 64;

    // layer 1
    gather_kernel<<<gatherGrid, 256, 0, stream>>>(x0, row_ptr, csr_src, csr_w, agg, N);
    gemm_dual<<<gemmGrid, 256, 0, stream>>>(agg, x0, W1r, W1t, b1, buf0, N);
    // layer 2
    gather_kernel<<<gatherGrid, 256, 0, stream>>>(buf0, row_ptr, csr_src, csr_w, agg, N);
    gemm_dual<<<gemmGrid, 256, 0, stream>>>(agg, buf0, W2r, W2t, b2, buf1, N);
    // layer 3
    gather_kernel<<<gatherGrid, 256, 0, stream>>>(buf1, row_ptr, csr_src, csr_w, agg, N);
    gemm_dual<<<gemmGrid, 256, 0, stream>>>(agg, buf1, W3r, W3t, b3, buf0, N);
    // head
    head_kernel<<<(N + 255) / 256, 256, 0, stream>>>(buf0, Wlin, blin, (float*)d_out, N);
}

// Round 2
// 899.851 us; speedup vs baseline: 1.2606x; 1.2606x over previous
//
#include <hip/hip_runtime.h>
#include <hip/hip_bf16.h>
#include <math.h>

#define C128 128
#define OUT_CH 10

__device__ __forceinline__ unsigned short f2bf(float f) {
    unsigned b = __float_as_uint(f);
    unsigned r = (b + 0x7FFF + ((b >> 16) & 1)) >> 16;   // RNE
    return (unsigned short)r;
}
__device__ __forceinline__ float bf2f(unsigned short u) {
    return __uint_as_float(((unsigned)u) << 16);
}

// ---------------- CSR build ----------------

__global__ void hist_kernel(const int* __restrict__ ei, int* __restrict__ deg, int E) {
    int e = blockIdx.x * blockDim.x + threadIdx.x;
    if (e < E) atomicAdd(&deg[ei[E + e]], 1);
}

// phase 1: per-tile (256 elems) sums
__global__ __launch_bounds__(256) void tile_sum_kernel(const int* __restrict__ deg,
                                                       int* __restrict__ tile_sums, int N) {
    __shared__ int red[256];
    int t = threadIdx.x;
    int i = blockIdx.x * 256 + t;
    red[t] = (i < N) ? deg[i] : 0;
    __syncthreads();
    for (int off = 128; off > 0; off >>= 1) {
        if (t < off) red[t] += red[t + off];
        __syncthreads();
    }
    if (t == 0) tile_sums[blockIdx.x] = red[0];
}

// phase 2: single-block exclusive scan of tile sums (numTiles <= 512)
__global__ __launch_bounds__(512) void tile_scan_kernel(const int* __restrict__ tile_sums,
                                                        int* __restrict__ tile_off, int numTiles) {
    __shared__ int s[512];
    int t = threadIdx.x;
    int v = (t < numTiles) ? tile_sums[t] : 0;
    s[t] = v;
    __syncthreads();
    for (int off = 1; off < 512; off <<= 1) {
        int u = (t >= off) ? s[t - off] : 0;
        __syncthreads();
        s[t] += u;
        __syncthreads();
    }
    if (t < numTiles) tile_off[t] = s[t] - v;
}

// phase 3: per-tile exclusive scan + offset -> row_ptr
__global__ __launch_bounds__(256) void scan_emit_kernel(const int* __restrict__ deg,
                                                        const int* __restrict__ tile_off,
                                                        int* __restrict__ row_ptr, int N, int E) {
    __shared__ int s[256];
    int t = threadIdx.x;
    int i = blockIdx.x * 256 + t;
    int v = (i < N) ? deg[i] : 0;
    s[t] = v;
    __syncthreads();
    for (int off = 1; off < 256; off <<= 1) {
        int u = (t >= off) ? s[t - off] : 0;
        __syncthreads();
        s[t] += u;
        __syncthreads();
    }
    if (i < N) row_ptr[i] = tile_off[blockIdx.x] + s[t] - v;
    if (blockIdx.x == 0 && t == 0) row_ptr[N] = E;
}

__global__ void copy_int(const int* __restrict__ a, int* __restrict__ b, int n) {
    int i = blockIdx.x * blockDim.x + threadIdx.x;
    if (i < n) b[i] = a[i];
}

__global__ void fill_kernel(const int* __restrict__ ei, const float* __restrict__ ew,
                            int* __restrict__ cursor, int* __restrict__ csr_src,
                            float* __restrict__ csr_w, int E) {
    int e = blockIdx.x * blockDim.x + threadIdx.x;
    if (e < E) {
        int dst = ei[E + e];
        int pos = atomicAdd(&cursor[dst], 1);
        csr_src[pos] = ei[e];
        csr_w[pos] = ew[e];
    }
}

// ---------------- fp32 -> bf16 conversion (layer-1 input only) ----------------

__global__ __launch_bounds__(256) void cvt_bf16_kernel(const float4* __restrict__ x,
                                                       ushort4* __restrict__ xb, int n4) {
    int i = blockIdx.x * blockDim.x + threadIdx.x;
    if (i < n4) {
        float4 v = x[i];
        ushort4 o;
        o.x = f2bf(v.x); o.y = f2bf(v.y); o.z = f2bf(v.z); o.w = f2bf(v.w);
        xb[i] = o;
    }
}

// ---------------- aggregation: one wave per node, 2 edges/iter, bf16 reads ----------------

__global__ __launch_bounds__(256) void gather_bf16_kernel(
    const unsigned short* __restrict__ xb, const int* __restrict__ row_ptr,
    const int* __restrict__ csr_src, const float* __restrict__ csr_w,
    float* __restrict__ agg, int N)
{
    int node = blockIdx.x * 4 + (threadIdx.x >> 6);
    if (node >= N) return;
    int lane = threadIdx.x & 63;
    int half = lane >> 5;       // which edge of the pair
    int l32  = lane & 31;       // channel group (4 ch)
    int i  = row_ptr[node] + half;
    int e1 = row_ptr[node + 1];
    float4 acc = make_float4(0.f, 0.f, 0.f, 0.f);
    for (; i < e1; i += 2) {
        int s   = csr_src[i];
        float w = csr_w[i];
        ushort4 raw = *(const ushort4*)&xb[(size_t)s * C128 + l32 * 4];
        acc.x += bf2f(raw.x) * w;
        acc.y += bf2f(raw.y) * w;
        acc.z += bf2f(raw.z) * w;
        acc.w += bf2f(raw.w) * w;
    }
    acc.x += __shfl_xor(acc.x, 32, 64);
    acc.y += __shfl_xor(acc.y, 32, 64);
    acc.z += __shfl_xor(acc.z, 32, 64);
    acc.w += __shfl_xor(acc.w, 32, 64);
    if (half == 0)
        *(float4*)&agg[(size_t)node * C128 + l32 * 4] = acc;
}

// ---------------- fused dual GEMM + bias + relu (+ optional bf16 copy out) ----------------

__global__ __launch_bounds__(256) void gemm_dual(
    const float* __restrict__ A, const float* __restrict__ X,
    const float* __restrict__ Wr, const float* __restrict__ Wt,
    const float* __restrict__ bias, float* __restrict__ out,
    unsigned short* __restrict__ out_b, int N)
{
    __shared__ float Wl[32][128];   // 16 KB
    __shared__ float Il[64][36];    // 9.2 KB, stride 36 breaks bank aliasing
    const int t = threadIdx.x;
    const int node0 = blockIdx.x * 64;
    const int jr = t >> 5;          // 0..7
    const int cg = t & 31;          // float4 column group

    float4 acc[8];
#pragma unroll
    for (int j = 0; j < 8; ++j) acc[j] = make_float4(0.f, 0.f, 0.f, 0.f);

    for (int chunk = 0; chunk < 8; ++chunk) {
        const float* Wsrc = (chunk < 4) ? Wr : Wt;
        const float* Isrc = (chunk < 4) ? A  : X;
        const int k0 = (chunk & 3) * 32;
        __syncthreads();
#pragma unroll
        for (int i = 0; i < 4; ++i) {
            int idx = t + 256 * i;
            int r = idx >> 5, c = idx & 31;
            *(float4*)&Wl[r][c * 4] = *(const float4*)&Wsrc[(size_t)(k0 + r) * C128 + c * 4];
        }
#pragma unroll
        for (int i = 0; i < 2; ++i) {
            int idx = t + 256 * i;
            int r = idx >> 3, c = idx & 7;
            int nn = node0 + r;
            float4 v = make_float4(0.f, 0.f, 0.f, 0.f);
            if (nn < N) v = *(const float4*)&Isrc[(size_t)nn * C128 + k0 + c * 4];
            *(float4*)&Il[r][c * 4] = v;
        }
        __syncthreads();
#pragma unroll
        for (int k = 0; k < 32; k += 4) {
            float4 av[8];
#pragma unroll
            for (int j = 0; j < 8; ++j) av[j] = *(float4*)&Il[jr + 8 * j][k];
#pragma unroll
            for (int kk = 0; kk < 4; ++kk) {
                float4 w = *(float4*)&Wl[k + kk][cg * 4];
#pragma unroll
                for (int j = 0; j < 8; ++j) {
                    float aj = (kk == 0) ? av[j].x : (kk == 1) ? av[j].y
                             : (kk == 2) ? av[j].z : av[j].w;
                    acc[j].x += aj * w.x;
                    acc[j].y += aj * w.y;
                    acc[j].z += aj * w.z;
                    acc[j].w += aj * w.w;
                }
            }
        }
    }

    float4 bv = *(const float4*)&bias[cg * 4];
#pragma unroll
    for (int j = 0; j < 8; ++j) {
        int nn = node0 + jr + 8 * j;
        if (nn < N) {
            float4 f;
            f.x = fmaxf(acc[j].x + bv.x, 0.f);
            f.y = fmaxf(acc[j].y + bv.y, 0.f);
            f.z = fmaxf(acc[j].z + bv.z, 0.f);
            f.w = fmaxf(acc[j].w + bv.w, 0.f);
            *(float4*)&out[(size_t)nn * C128 + cg * 4] = f;
            if (out_b) {
                ushort4 o;
                o.x = f2bf(f.x); o.y = f2bf(f.y); o.z = f2bf(f.z); o.w = f2bf(f.w);
                *(ushort4*)&out_b[(size_t)nn * C128 + cg * 4] = o;
            }
        }
    }
}

// ---------------- head: x3 @ W_lin + b_lin, log_softmax ----------------

__global__ __launch_bounds__(256) void head_kernel(
    const float* __restrict__ x, const float* __restrict__ Wl,
    const float* __restrict__ bl, float* __restrict__ out, int N)
{
    int n = blockIdx.x * blockDim.x + threadIdx.x;
    if (n >= N) return;
    float acc[OUT_CH];
#pragma unroll
    for (int c = 0; c < OUT_CH; ++c) acc[c] = bl[c];
    const float4* row = (const float4*)(x + (size_t)n * C128);
#pragma unroll 4
    for (int kk = 0; kk < 32; ++kk) {
        float4 v = row[kk];
        int k = kk * 4;
#pragma unroll
        for (int c = 0; c < OUT_CH; ++c) {
            acc[c] += v.x * Wl[(k + 0) * OUT_CH + c]
                    + v.y * Wl[(k + 1) * OUT_CH + c]
                    + v.z * Wl[(k + 2) * OUT_CH + c]
                    + v.w * Wl[(k + 3) * OUT_CH + c];
        }
    }
    float m = acc[0];
#pragma unroll
    for (int c = 1; c < OUT_CH; ++c) m = fmaxf(m, acc[c]);
    float s = 0.f;
#pragma unroll
    for (int c = 0; c < OUT_CH; ++c) s += __expf(acc[c] - m);
    float lse = m + __logf(s);
#pragma unroll
    for (int c = 0; c < OUT_CH; ++c) out[(size_t)n * OUT_CH + c] = acc[c] - lse;
}

// ---------------- launch ----------------

extern "C" void kernel_launch(void* const* d_in, const int* in_sizes, int n_in,
                              void* d_out, int out_size, void* d_ws, size_t ws_size,
                              hipStream_t stream) {
    const float* x0   = (const float*)d_in[0];
    const int*   ei   = (const int*)  d_in[1];
    const float* ew   = (const float*)d_in[2];
    const float* W1r  = (const float*)d_in[3];
    const float* b1   = (const float*)d_in[4];
    const float* W1t  = (const float*)d_in[5];
    const float* W2r  = (const float*)d_in[6];
    const float* b2   = (const float*)d_in[7];
    const float* W2t  = (const float*)d_in[8];
    const float* W3r  = (const float*)d_in[9];
    const float* b3   = (const float*)d_in[10];
    const float* W3t  = (const float*)d_in[11];
    const float* Wlin = (const float*)d_in[12];
    const float* blin = (const float*)d_in[13];

    const int N = in_sizes[0] / C128;
    const int E = in_sizes[1] / 2;
    const int numTiles = (N + 255) / 256;

    char* ws = (char*)d_ws;
    size_t fbytes = (size_t)N * C128 * sizeof(float);     // 51.2 MB
    size_t bbytes = (size_t)N * C128 * sizeof(unsigned short); // 25.6 MB
    float*          agg       = (float*)(ws);
    float*          buf0      = (float*)(ws + fbytes);
    float*          buf1      = (float*)(ws + 2 * fbytes);
    unsigned short* xb        = (unsigned short*)(ws + 3 * fbytes);
    float*          csr_w     = (float*)(ws + 3 * fbytes + bbytes);
    int*            csr_src   = (int*)  (ws + 3 * fbytes + bbytes + (size_t)E * 4);
    int*            row_ptr   = csr_src + E;
    int*            cursor    = row_ptr + (N + 1);       // doubles as deg histogram
    int*            tile_sums = cursor + N;
    int*            tile_off  = tile_sums + 512;

    // build CSR (dst-indexed), once per call, reused by all 3 layers
    hipMemsetAsync(cursor, 0, (size_t)N * sizeof(int), stream);
    hist_kernel<<<(E + 255) / 256, 256, 0, stream>>>(ei, cursor, E);
    tile_sum_kernel<<<numTiles, 256, 0, stream>>>(cursor, tile_sums, N);
    tile_scan_kernel<<<1, 512, 0, stream>>>(tile_sums, tile_off, numTiles);
    scan_emit_kernel<<<numTiles, 256, 0, stream>>>(cursor, tile_off, row_ptr, N, E);
    copy_int<<<(N + 255) / 256, 256, 0, stream>>>(row_ptr, cursor, N);
    fill_kernel<<<(E + 255) / 256, 256, 0, stream>>>(ei, ew, cursor, csr_src, csr_w, E);

    // bf16 copy of layer-1 input
    cvt_bf16_kernel<<<(N * C128 / 4 + 255) / 256, 256, 0, stream>>>(
        (const float4*)x0, (ushort4*)xb, N * C128 / 4);

    int gatherGrid = (N + 3) / 4;
    int gemmGrid   = (N + 63) / 64;

    // layer 1
    gather_bf16_kernel<<<gatherGrid, 256, 0, stream>>>(xb, row_ptr, csr_src, csr_w, agg, N);
    gemm_dual<<<gemmGrid, 256, 0, stream>>>(agg, x0, W1r, W1t, b1, buf0, xb, N);
    // layer 2 (xb now holds bf16(buf0))
    gather_bf16_kernel<<<gatherGrid, 256, 0, stream>>>(xb, row_ptr, csr_src, csr_w, agg, N);
    gemm_dual<<<gemmGrid, 256, 0, stream>>>(agg, buf0, W2r, W2t, b2, buf1, xb, N);
    // layer 3
    gather_bf16_kernel<<<gatherGrid, 256, 0, stream>>>(xb, row_ptr, csr_src, csr_w, agg, N);
    gemm_dual<<<gemmGrid, 256, 0, stream>>>(agg, buf1, W3r, W3t, b3, buf0, nullptr, N);
    // head
    head_kernel<<<(N + 255) / 256, 256, 0, stream>>>(buf0, Wlin, blin, (float*)d_out, N);
}

// Round 4
// 702.892 us; speedup vs baseline: 1.6138x; 1.2802x over previous
//
#include <hip/hip_runtime.h>
#include <hip/hip_bf16.h>
#include <math.h>

#define C128 128
#define OUT_CH 10

typedef __attribute__((ext_vector_type(8))) short short8;
typedef __attribute__((ext_vector_type(4))) float f32x4;

__device__ __forceinline__ unsigned short f2bf(float f) {
    unsigned b = __float_as_uint(f);
    unsigned r = (b + 0x7FFF + ((b >> 16) & 1)) >> 16;   // RNE
    return (unsigned short)r;
}
__device__ __forceinline__ float bf2f(unsigned short u) {
    return __uint_as_float(((unsigned)u) << 16);
}

// ---------------- CSR build ----------------

__global__ void hist_kernel(const int* __restrict__ ei, int* __restrict__ deg, int E) {
    int e = blockIdx.x * blockDim.x + threadIdx.x;
    if (e < E) atomicAdd(&deg[ei[E + e]], 1);
}

__global__ __launch_bounds__(256) void tile_sum_kernel(const int* __restrict__ deg,
                                                       int* __restrict__ tile_sums, int N) {
    __shared__ int red[256];
    int t = threadIdx.x;
    int i = blockIdx.x * 256 + t;
    red[t] = (i < N) ? deg[i] : 0;
    __syncthreads();
    for (int off = 128; off > 0; off >>= 1) {
        if (t < off) red[t] += red[t + off];
        __syncthreads();
    }
    if (t == 0) tile_sums[blockIdx.x] = red[0];
}

__global__ __launch_bounds__(512) void tile_scan_kernel(const int* __restrict__ tile_sums,
                                                        int* __restrict__ tile_off, int numTiles) {
    __shared__ int s[512];
    int t = threadIdx.x;
    int v = (t < numTiles) ? tile_sums[t] : 0;
    s[t] = v;
    __syncthreads();
    for (int off = 1; off < 512; off <<= 1) {
        int u = (t >= off) ? s[t - off] : 0;
        __syncthreads();
        s[t] += u;
        __syncthreads();
    }
    if (t < numTiles) tile_off[t] = s[t] - v;
}

__global__ __launch_bounds__(256) void scan_emit_kernel(const int* __restrict__ deg,
                                                        const int* __restrict__ tile_off,
                                                        int* __restrict__ row_ptr, int N, int E) {
    __shared__ int s[256];
    int t = threadIdx.x;
    int i = blockIdx.x * 256 + t;
    int v = (i < N) ? deg[i] : 0;
    s[t] = v;
    __syncthreads();
    for (int off = 1; off < 256; off <<= 1) {
        int u = (t >= off) ? s[t - off] : 0;
        __syncthreads();
        s[t] += u;
        __syncthreads();
    }
    if (i < N) row_ptr[i] = tile_off[blockIdx.x] + s[t] - v;
    if (blockIdx.x == 0 && t == 0) row_ptr[N] = E;
}

__global__ void copy_int(const int* __restrict__ a, int* __restrict__ b, int n) {
    int i = blockIdx.x * blockDim.x + threadIdx.x;
    if (i < n) b[i] = a[i];
}

__global__ void fill_kernel(const int* __restrict__ ei, const float* __restrict__ ew,
                            int* __restrict__ cursor, int* __restrict__ csr_src,
                            float* __restrict__ csr_w, int E) {
    int e = blockIdx.x * blockDim.x + threadIdx.x;
    if (e < E) {
        int dst = ei[E + e];
        int pos = atomicAdd(&cursor[dst], 1);
        csr_src[pos] = ei[e];
        csr_w[pos] = ew[e];
    }
}

// ---------------- fp32 -> bf16 conversion (layer-1 input) ----------------

__global__ __launch_bounds__(256) void cvt_bf16_kernel(const float4* __restrict__ x,
                                                       ushort4* __restrict__ xb, int n4) {
    int i = blockIdx.x * blockDim.x + threadIdx.x;
    if (i < n4) {
        float4 v = x[i];
        ushort4 o;
        o.x = f2bf(v.x); o.y = f2bf(v.y); o.z = f2bf(v.z); o.w = f2bf(v.w);
        xb[i] = o;
    }
}

// ---------------- weight pack: [Wr;Wt] (256x128 fp32) -> MFMA B-frag order bf16 ----------------
// flat idx = ((ks*4 + quad)*128 + n)*8 + j  holds  W[k = (ks%4)*32 + quad*8 + j][n]
// (ks<4 -> Wr, ks>=4 -> Wt)

__global__ __launch_bounds__(256) void pack_w_kernel(const float* __restrict__ Wr,
                                                     const float* __restrict__ Wt,
                                                     unsigned short* __restrict__ Wp) {
    int idx = blockIdx.x * 256 + threadIdx.x;     // 32768
    int j    = idx & 7;
    int n    = (idx >> 3) & 127;
    int quad = (idx >> 10) & 3;
    int ks   = idx >> 12;
    const float* W = (ks < 4) ? Wr : Wt;
    int k = (ks & 3) * 32 + quad * 8 + j;
    Wp[idx] = f2bf(W[(size_t)k * C128 + n]);
}

// ---------------- aggregation: one wave per node, 2 edges/iter, bf16 in/out ----------------

__global__ __launch_bounds__(256) void gather_bf16_kernel(
    const unsigned short* __restrict__ xb, const int* __restrict__ row_ptr,
    const int* __restrict__ csr_src, const float* __restrict__ csr_w,
    unsigned short* __restrict__ aggb, int N)
{
    int node = blockIdx.x * 4 + (threadIdx.x >> 6);
    if (node >= N) return;
    int lane = threadIdx.x & 63;
    int half = lane >> 5;       // which edge of the pair
    int l32  = lane & 31;       // channel group (4 ch)
    int i  = row_ptr[node] + half;
    int e1 = row_ptr[node + 1];
    float4 acc = make_float4(0.f, 0.f, 0.f, 0.f);
    for (; i < e1; i += 2) {
        int s   = csr_src[i];
        float w = csr_w[i];
        ushort4 raw = *(const ushort4*)&xb[(size_t)s * C128 + l32 * 4];
        acc.x += bf2f(raw.x) * w;
        acc.y += bf2f(raw.y) * w;
        acc.z += bf2f(raw.z) * w;
        acc.w += bf2f(raw.w) * w;
    }
    acc.x += __shfl_xor(acc.x, 32, 64);
    acc.y += __shfl_xor(acc.y, 32, 64);
    acc.z += __shfl_xor(acc.z, 32, 64);
    acc.w += __shfl_xor(acc.w, 32, 64);
    if (half == 0) {
        ushort4 o;
        o.x = f2bf(acc.x); o.y = f2bf(acc.y); o.z = f2bf(acc.z); o.w = f2bf(acc.w);
        *(ushort4*)&aggb[(size_t)node * C128 + l32 * 4] = o;
    }
}

// ---------------- MFMA dual GEMM: out = relu([aggb|xb] @ [Wr;Wt] + b), bf16 out ----------------
// Block: 64 nodes x 128 ch, 256 threads (4 waves). Wave w -> rows w*16..+15, 8 n-tiles.
// K = 256 in 8 chunks of 32 (ks 0..3 from aggb, 4..7 from xb).

#define A_STRIDE 40   // bf16 elements per staged row (32 data + 8 pad; 80 B, 16B-aligned, <=2-way banks)

__global__ __launch_bounds__(256) void gemm_mfma(
    const unsigned short* __restrict__ aggb, const unsigned short* __restrict__ xb,
    const unsigned short* __restrict__ Wp, const float* __restrict__ bias,
    unsigned short* __restrict__ outb, int N)
{
    __shared__ unsigned short WL[8 * 4 * 128 * 8];   // 64 KB, full packed weights
    __shared__ unsigned short AL[64 * A_STRIDE];     // 5 KB, one 64x32 A chunk

    const int t = threadIdx.x;
    const int node0 = blockIdx.x * 64;
    const int w    = t >> 6;
    const int lane = t & 63;
    const int l15  = lane & 15;
    const int quad = lane >> 4;

    // stage full packed W: 32768 ushorts = 4096 x uint4 (16 iters x 256 threads)
#pragma unroll
    for (int i = 0; i < 16; ++i) {
        int slot = i * 256 + t;
        *(uint4*)&WL[slot * 8] = *(const uint4*)&Wp[slot * 8];
    }

    // preload bias for this lane's columns
    float bv[8];
#pragma unroll
    for (int nt = 0; nt < 8; ++nt) bv[nt] = bias[nt * 16 + l15];

    f32x4 acc[8];
#pragma unroll
    for (int nt = 0; nt < 8; ++nt) acc[nt] = (f32x4){0.f, 0.f, 0.f, 0.f};

    // A staging slot for this thread: row r, 8-elem group c
    const int sr = t >> 2;        // 0..63
    const int sc = t & 3;         // 0..3
    const int srow = node0 + sr;

    for (int ks = 0; ks < 8; ++ks) {
        const unsigned short* Asrc = (ks < 4) ? aggb : xb;
        const int koff = (ks & 3) * 32;
        __syncthreads();
        uint4 av = make_uint4(0u, 0u, 0u, 0u);
        if (srow < N) av = *(const uint4*)&Asrc[(size_t)srow * C128 + koff + sc * 8];
        *(uint4*)&AL[sr * A_STRIDE + sc * 8] = av;
        __syncthreads();

        short8 a = *(const short8*)&AL[(w * 16 + l15) * A_STRIDE + quad * 8];
#pragma unroll
        for (int nt = 0; nt < 8; ++nt) {
            short8 b = *(const short8*)&WL[(((ks * 4 + quad) * 128) + nt * 16 + l15) * 8];
            acc[nt] = __builtin_amdgcn_mfma_f32_16x16x32_bf16(a, b, acc[nt], 0, 0, 0);
        }
    }

    // epilogue: D[row][col], row = w*16 + quad*4 + r, col = nt*16 + l15
#pragma unroll
    for (int r = 0; r < 4; ++r) {
        int row = node0 + w * 16 + quad * 4 + r;
        if (row < N) {
#pragma unroll
            for (int nt = 0; nt < 8; ++nt) {
                float v = fmaxf(acc[nt][r] + bv[nt], 0.f);
                outb[(size_t)row * C128 + nt * 16 + l15] = f2bf(v);
            }
        }
    }
}

// ---------------- head: bf16 x3 @ W_lin + b_lin, log_softmax ----------------

__global__ __launch_bounds__(256) void head_kernel(
    const unsigned short* __restrict__ x, const float* __restrict__ Wl,
    const float* __restrict__ bl, float* __restrict__ out, int N)
{
    int n = blockIdx.x * blockDim.x + threadIdx.x;
    if (n >= N) return;
    float acc[OUT_CH];
#pragma unroll
    for (int c = 0; c < OUT_CH; ++c) acc[c] = bl[c];
    const ushort4* row = (const ushort4*)(x + (size_t)n * C128);
#pragma unroll 4
    for (int kk = 0; kk < 32; ++kk) {
        ushort4 u = row[kk];
        float vx = bf2f(u.x), vy = bf2f(u.y), vz = bf2f(u.z), vw = bf2f(u.w);
        int k = kk * 4;
#pragma unroll
        for (int c = 0; c < OUT_CH; ++c) {
            acc[c] += vx * Wl[(k + 0) * OUT_CH + c]
                    + vy * Wl[(k + 1) * OUT_CH + c]
                    + vz * Wl[(k + 2) * OUT_CH + c]
                    + vw * Wl[(k + 3) * OUT_CH + c];
        }
    }
    float m = acc[0];
#pragma unroll
    for (int c = 1; c < OUT_CH; ++c) m = fmaxf(m, acc[c]);
    float s = 0.f;
#pragma unroll
    for (int c = 0; c < OUT_CH; ++c) s += __expf(acc[c] - m);
    float lse = m + __logf(s);
#pragma unroll
    for (int c = 0; c < OUT_CH; ++c) out[(size_t)n * OUT_CH + c] = acc[c] - lse;
}

// ---------------- launch ----------------

extern "C" void kernel_launch(void* const* d_in, const int* in_sizes, int n_in,
                              void* d_out, int out_size, void* d_ws, size_t ws_size,
                              hipStream_t stream) {
    const float* x0   = (const float*)d_in[0];
    const int*   ei   = (const int*)  d_in[1];
    const float* ew   = (const float*)d_in[2];
    const float* W1r  = (const float*)d_in[3];
    const float* b1   = (const float*)d_in[4];
    const float* W1t  = (const float*)d_in[5];
    const float* W2r  = (const float*)d_in[6];
    const float* b2   = (const float*)d_in[7];
    const float* W2t  = (const float*)d_in[8];
    const float* W3r  = (const float*)d_in[9];
    const float* b3   = (const float*)d_in[10];
    const float* W3t  = (const float*)d_in[11];
    const float* Wlin = (const float*)d_in[12];
    const float* blin = (const float*)d_in[13];

    const int N = in_sizes[0] / C128;
    const int E = in_sizes[1] / 2;
    const int numTiles = (N + 255) / 256;

    char* ws = (char*)d_ws;
    size_t bb = (size_t)N * C128 * sizeof(unsigned short);   // 25.6 MB
    unsigned short* aggb = (unsigned short*)(ws);
    unsigned short* xb0  = (unsigned short*)(ws + bb);
    unsigned short* xb1  = (unsigned short*)(ws + 2 * bb);
    unsigned short* Wp1  = (unsigned short*)(ws + 3 * bb);   // 3 x 32768 ushorts
    unsigned short* Wp2  = Wp1 + 32768;
    unsigned short* Wp3  = Wp2 + 32768;
    float* csr_w   = (float*)(ws + 3 * bb + 3 * 32768 * sizeof(unsigned short));
    int*   csr_src = (int*)(csr_w + E);
    int*   row_ptr = csr_src + E;
    int*   cursor  = row_ptr + (N + 1);
    int*   tile_sums = cursor + N;
    int*   tile_off  = tile_sums + 512;

    // build CSR (dst-indexed), once per call
    hipMemsetAsync(cursor, 0, (size_t)N * sizeof(int), stream);
    hist_kernel<<<(E + 255) / 256, 256, 0, stream>>>(ei, cursor, E);
    tile_sum_kernel<<<numTiles, 256, 0, stream>>>(cursor, tile_sums, N);
    tile_scan_kernel<<<1, 512, 0, stream>>>(tile_sums, tile_off, numTiles);
    scan_emit_kernel<<<numTiles, 256, 0, stream>>>(cursor, tile_off, row_ptr, N, E);
    copy_int<<<(N + 255) / 256, 256, 0, stream>>>(row_ptr, cursor, N);
    fill_kernel<<<(E + 255) / 256, 256, 0, stream>>>(ei, ew, cursor, csr_src, csr_w, E);

    // bf16 input + packed weights
    cvt_bf16_kernel<<<(N * C128 / 4 + 255) / 256, 256, 0, stream>>>(
        (const float4*)x0, (ushort4*)xb0, N * C128 / 4);
    pack_w_kernel<<<128, 256, 0, stream>>>(W1r, W1t, Wp1);
    pack_w_kernel<<<128, 256, 0, stream>>>(W2r, W2t, Wp2);
    pack_w_kernel<<<128, 256, 0, stream>>>(W3r, W3t, Wp3);

    int gatherGrid = (N + 3) / 4;
    int gemmGrid   = (N + 63) / 64;

    // layer 1
    gather_bf16_kernel<<<gatherGrid, 256, 0, stream>>>(xb0, row_ptr, csr_src, csr_w, aggb, N);
    gemm_mfma<<<gemmGrid, 256, 0, stream>>>(aggb, xb0, Wp1, b1, xb1, N);
    // layer 2
    gather_bf16_kernel<<<gatherGrid, 256, 0, stream>>>(xb1, row_ptr, csr_src, csr_w, aggb, N);
    gemm_mfma<<<gemmGrid, 256, 0, stream>>>(aggb, xb1, Wp2, b2, xb0, N);
    // layer 3
    gather_bf16_kernel<<<gatherGrid, 256, 0, stream>>>(xb0, row_ptr, csr_src, csr_w, aggb, N);
    gemm_mfma<<<gemmGrid, 256, 0, stream>>>(aggb, xb0, Wp3, b3, xb1, N);
    // head
    head_kernel<<<(N + 255) / 256, 256, 0, stream>>>(xb1, Wlin, blin, (float*)d_out, N);
}

// Round 5
// 604.907 us; speedup vs baseline: 1.8752x; 1.1620x over previous
//
#include <hip/hip_runtime.h>
#include <hip/hip_bf16.h>
#include <math.h>

#define C128 128
#define OUT_CH 10

typedef __attribute__((ext_vector_type(8))) short short8;
typedef __attribute__((ext_vector_type(8))) unsigned short ushort8v;
typedef __attribute__((ext_vector_type(4))) float f32x4;

__device__ __forceinline__ unsigned short f2bf(float f) {
    unsigned b = __float_as_uint(f);
    unsigned r = (b + 0x7FFF + ((b >> 16) & 1)) >> 16;   // RNE
    return (unsigned short)r;
}
__device__ __forceinline__ float bf2f(unsigned short u) {
    return __uint_as_float(((unsigned)u) << 16);
}

// ---------------- CSR build ----------------

__global__ void hist_kernel(const int* __restrict__ ei, int* __restrict__ deg, int E) {
    int e = blockIdx.x * blockDim.x + threadIdx.x;
    if (e < E) atomicAdd(&deg[ei[E + e]], 1);
}

__global__ __launch_bounds__(256) void tile_sum_kernel(const int* __restrict__ deg,
                                                       int* __restrict__ tile_sums, int N) {
    __shared__ int red[256];
    int t = threadIdx.x;
    int i = blockIdx.x * 256 + t;
    red[t] = (i < N) ? deg[i] : 0;
    __syncthreads();
    for (int off = 128; off > 0; off >>= 1) {
        if (t < off) red[t] += red[t + off];
        __syncthreads();
    }
    if (t == 0) tile_sums[blockIdx.x] = red[0];
}

__global__ __launch_bounds__(512) void tile_scan_kernel(const int* __restrict__ tile_sums,
                                                        int* __restrict__ tile_off, int numTiles) {
    __shared__ int s[512];
    int t = threadIdx.x;
    int v = (t < numTiles) ? tile_sums[t] : 0;
    s[t] = v;
    __syncthreads();
    for (int off = 1; off < 512; off <<= 1) {
        int u = (t >= off) ? s[t - off] : 0;
        __syncthreads();
        s[t] += u;
        __syncthreads();
    }
    if (t < numTiles) tile_off[t] = s[t] - v;
}

// per-tile exclusive scan + offset -> row_ptr; ALSO overwrites deg[] with the
// same offset to serve as fill's cursor (each element is read exactly once by
// its own thread before being overwritten -> no race).
__global__ __launch_bounds__(256) void scan_emit_kernel(int* __restrict__ deg_cursor,
                                                        const int* __restrict__ tile_off,
                                                        int* __restrict__ row_ptr, int N, int E) {
    __shared__ int s[256];
    int t = threadIdx.x;
    int i = blockIdx.x * 256 + t;
    int v = (i < N) ? deg_cursor[i] : 0;
    s[t] = v;
    __syncthreads();
    for (int off = 1; off < 256; off <<= 1) {
        int u = (t >= off) ? s[t - off] : 0;
        __syncthreads();
        s[t] += u;
        __syncthreads();
    }
    if (i < N) {
        int o = tile_off[blockIdx.x] + s[t] - v;
        row_ptr[i] = o;
        deg_cursor[i] = o;
    }
    if (blockIdx.x == 0 && t == 0) row_ptr[N] = E;
}

__global__ void fill_kernel(const int* __restrict__ ei, const float* __restrict__ ew,
                            int* __restrict__ cursor, int2* __restrict__ csr, int E) {
    int e = blockIdx.x * blockDim.x + threadIdx.x;
    if (e < E) {
        int dst = ei[E + e];
        int pos = atomicAdd(&cursor[dst], 1);
        csr[pos] = make_int2(ei[e], __float_as_int(ew[e]));
    }
}

// ---------------- fp32 -> bf16 conversion (layer-1 input) ----------------

__global__ __launch_bounds__(256) void cvt_bf16_kernel(const float4* __restrict__ x,
                                                       ushort4* __restrict__ xb, int n4) {
    int i = blockIdx.x * blockDim.x + threadIdx.x;
    if (i < n4) {
        float4 v = x[i];
        ushort4 o;
        o.x = f2bf(v.x); o.y = f2bf(v.y); o.z = f2bf(v.z); o.w = f2bf(v.w);
        xb[i] = o;
    }
}

// ---------------- weight pack: [Wr;Wt] (256x128 fp32) -> MFMA B-frag order bf16 ----------------

__global__ __launch_bounds__(256) void pack_w_kernel(const float* __restrict__ Wr,
                                                     const float* __restrict__ Wt,
                                                     unsigned short* __restrict__ Wp) {
    int idx = blockIdx.x * 256 + threadIdx.x;     // 32768
    int j    = idx & 7;
    int n    = (idx >> 3) & 127;
    int quad = (idx >> 10) & 3;
    int ks   = idx >> 12;
    const float* W = (ks < 4) ? Wr : Wt;
    int k = (ks & 3) * 32 + quad * 8 + j;
    Wp[idx] = f2bf(W[(size_t)k * C128 + n]);
}

// ---------------- aggregation: one wave per node, 4 edges/iter, 16B loads ----------------

__global__ __launch_bounds__(256) void gather_bf16_kernel(
    const unsigned short* __restrict__ xb, const int* __restrict__ row_ptr,
    const int2* __restrict__ csr, unsigned short* __restrict__ aggb, int N)
{
    int node = blockIdx.x * 4 + (threadIdx.x >> 6);
    if (node >= N) return;
    int lane = threadIdx.x & 63;
    int g   = lane >> 4;        // edge group 0..3
    int l16 = lane & 15;        // channel group (8 bf16 = 16 B)
    int i  = row_ptr[node] + g;
    int e1 = row_ptr[node + 1];
    float acc[8];
#pragma unroll
    for (int j = 0; j < 8; ++j) acc[j] = 0.f;
    for (; i < e1; i += 4) {
        int2 rec = csr[i];
        float w = __int_as_float(rec.y);
        ushort8v raw = *(const ushort8v*)&xb[(size_t)rec.x * C128 + l16 * 8];
#pragma unroll
        for (int j = 0; j < 8; ++j) acc[j] += bf2f(raw[j]) * w;
    }
#pragma unroll
    for (int j = 0; j < 8; ++j) {
        acc[j] += __shfl_xor(acc[j], 16, 64);
        acc[j] += __shfl_xor(acc[j], 32, 64);
    }
    if (g == 0) {
        ushort8v o;
#pragma unroll
        for (int j = 0; j < 8; ++j) o[j] = f2bf(acc[j]);
        *(ushort8v*)&aggb[(size_t)node * C128 + l16 * 8] = o;
    }
}

// ---------------- MFMA dual GEMM: out = relu([aggb|xb] @ [Wr;Wt] + b), bf16 out ----------------

#define A_STRIDE 40   // bf16 elements per staged row (32 data + 8 pad)

__global__ __launch_bounds__(256) void gemm_mfma(
    const unsigned short* __restrict__ aggb, const unsigned short* __restrict__ xb,
    const unsigned short* __restrict__ Wp, const float* __restrict__ bias,
    unsigned short* __restrict__ outb, int N)
{
    __shared__ unsigned short WL[8 * 4 * 128 * 8];   // 64 KB, full packed weights
    __shared__ unsigned short AL[64 * A_STRIDE];     // 5 KB, one 64x32 A chunk

    const int t = threadIdx.x;
    const int node0 = blockIdx.x * 64;
    const int w    = t >> 6;
    const int lane = t & 63;
    const int l15  = lane & 15;
    const int quad = lane >> 4;

    // stage full packed W: 32768 ushorts = 4096 x uint4
#pragma unroll
    for (int i = 0; i < 16; ++i) {
        int slot = i * 256 + t;
        *(uint4*)&WL[slot * 8] = *(const uint4*)&Wp[slot * 8];
    }

    float bv[8];
#pragma unroll
    for (int nt = 0; nt < 8; ++nt) bv[nt] = bias[nt * 16 + l15];

    f32x4 acc[8];
#pragma unroll
    for (int nt = 0; nt < 8; ++nt) acc[nt] = (f32x4){0.f, 0.f, 0.f, 0.f};

    const int sr = t >> 2;        // 0..63
    const int sc = t & 3;         // 0..3
    const int srow = node0 + sr;

    for (int ks = 0; ks < 8; ++ks) {
        const unsigned short* Asrc = (ks < 4) ? aggb : xb;
        const int koff = (ks & 3) * 32;
        __syncthreads();
        uint4 av = make_uint4(0u, 0u, 0u, 0u);
        if (srow < N) av = *(const uint4*)&Asrc[(size_t)srow * C128 + koff + sc * 8];
        *(uint4*)&AL[sr * A_STRIDE + sc * 8] = av;
        __syncthreads();

        short8 a = *(const short8*)&AL[(w * 16 + l15) * A_STRIDE + quad * 8];
#pragma unroll
        for (int nt = 0; nt < 8; ++nt) {
            short8 b = *(const short8*)&WL[(((ks * 4 + quad) * 128) + nt * 16 + l15) * 8];
            acc[nt] = __builtin_amdgcn_mfma_f32_16x16x32_bf16(a, b, acc[nt], 0, 0, 0);
        }
    }

#pragma unroll
    for (int r = 0; r < 4; ++r) {
        int row = node0 + w * 16 + quad * 4 + r;
        if (row < N) {
#pragma unroll
            for (int nt = 0; nt < 8; ++nt) {
                float v = fmaxf(acc[nt][r] + bv[nt], 0.f);
                outb[(size_t)row * C128 + nt * 16 + l15] = f2bf(v);
            }
        }
    }
}

// ---------------- head: bf16 x3 @ W_lin + b_lin, log_softmax ----------------

__global__ __launch_bounds__(256) void head_kernel(
    const unsigned short* __restrict__ x, const float* __restrict__ Wl,
    const float* __restrict__ bl, float* __restrict__ out, int N)
{
    int n = blockIdx.x * blockDim.x + threadIdx.x;
    if (n >= N) return;
    float acc[OUT_CH];
#pragma unroll
    for (int c = 0; c < OUT_CH; ++c) acc[c] = bl[c];
    const ushort4* row = (const ushort4*)(x + (size_t)n * C128);
#pragma unroll 4
    for (int kk = 0; kk < 32; ++kk) {
        ushort4 u = row[kk];
        float vx = bf2f(u.x), vy = bf2f(u.y), vz = bf2f(u.z), vw = bf2f(u.w);
        int k = kk * 4;
#pragma unroll
        for (int c = 0; c < OUT_CH; ++c) {
            acc[c] += vx * Wl[(k + 0) * OUT_CH + c]
                    + vy * Wl[(k + 1) * OUT_CH + c]
                    + vz * Wl[(k + 2) * OUT_CH + c]
                    + vw * Wl[(k + 3) * OUT_CH + c];
        }
    }
    float m = acc[0];
#pragma unroll
    for (int c = 1; c < OUT_CH; ++c) m = fmaxf(m, acc[c]);
    float s = 0.f;
#pragma unroll
    for (int c = 0; c < OUT_CH; ++c) s += __expf(acc[c] - m);
    float lse = m + __logf(s);
#pragma unroll
    for (int c = 0; c < OUT_CH; ++c) out[(size_t)n * OUT_CH + c] = acc[c] - lse;
}

// ---------------- launch ----------------

extern "C" void kernel_launch(void* const* d_in, const int* in_sizes, int n_in,
                              void* d_out, int out_size, void* d_ws, size_t ws_size,
                              hipStream_t stream) {
    const float* x0   = (const float*)d_in[0];
    const int*   ei   = (const int*)  d_in[1];
    const float* ew   = (const float*)d_in[2];
    const float* W1r  = (const float*)d_in[3];
    const float* b1   = (const float*)d_in[4];
    const float* W1t  = (const float*)d_in[5];
    const float* W2r  = (const float*)d_in[6];
    const float* b2   = (const float*)d_in[7];
    const float* W2t  = (const float*)d_in[8];
    const float* W3r  = (const float*)d_in[9];
    const float* b3   = (const float*)d_in[10];
    const float* W3t  = (const float*)d_in[11];
    const float* Wlin = (const float*)d_in[12];
    const float* blin = (const float*)d_in[13];

    const int N = in_sizes[0] / C128;
    const int E = in_sizes[1] / 2;
    const int numTiles = (N + 255) / 256;

    char* ws = (char*)d_ws;
    size_t bb = (size_t)N * C128 * sizeof(unsigned short);   // 25.6 MB
    unsigned short* aggb = (unsigned short*)(ws);
    unsigned short* xb0  = (unsigned short*)(ws + bb);
    unsigned short* xb1  = (unsigned short*)(ws + 2 * bb);
    unsigned short* Wp1  = (unsigned short*)(ws + 3 * bb);   // 3 x 32768 ushorts
    unsigned short* Wp2  = Wp1 + 32768;
    unsigned short* Wp3  = Wp2 + 32768;
    int2*  csr     = (int2*)(ws + 3 * bb + 3 * 32768 * sizeof(unsigned short));
    int*   row_ptr = (int*)(csr + E);
    int*   cursor  = row_ptr + (N + 1);       // deg histogram, then fill cursor
    int*   tile_sums = cursor + N;
    int*   tile_off  = tile_sums + 512;

    // build CSR (dst-indexed), once per call
    hipMemsetAsync(cursor, 0, (size_t)N * sizeof(int), stream);
    hist_kernel<<<(E + 255) / 256, 256, 0, stream>>>(ei, cursor, E);
    tile_sum_kernel<<<numTiles, 256, 0, stream>>>(cursor, tile_sums, N);
    tile_scan_kernel<<<1, 512, 0, stream>>>(tile_sums, tile_off, numTiles);
    scan_emit_kernel<<<numTiles, 256, 0, stream>>>(cursor, tile_off, row_ptr, N, E);
    fill_kernel<<<(E + 255) / 256, 256, 0, stream>>>(ei, ew, cursor, csr, E);

    // bf16 input + packed weights
    cvt_bf16_kernel<<<(N * C128 / 4 + 255) / 256, 256, 0, stream>>>(
        (const float4*)x0, (ushort4*)xb0, N * C128 / 4);
    pack_w_kernel<<<128, 256, 0, stream>>>(W1r, W1t, Wp1);
    pack_w_kernel<<<128, 256, 0, stream>>>(W2r, W2t, Wp2);
    pack_w_kernel<<<128, 256, 0, stream>>>(W3r, W3t, Wp3);

    int gatherGrid = (N + 3) / 4;
    int gemmGrid   = (N + 63) / 64;

    // layer 1
    gather_bf16_kernel<<<gatherGrid, 256, 0, stream>>>(xb0, row_ptr, csr, aggb, N);
    gemm_mfma<<<gemmGrid, 256, 0, stream>>>(aggb, xb0, Wp1, b1, xb1, N);
    // layer 2
    gather_bf16_kernel<<<gatherGrid, 256, 0, stream>>>(xb1, row_ptr, csr, aggb, N);
    gemm_mfma<<<gemmGrid, 256, 0, stream>>>(aggb, xb1, Wp2, b2, xb0, N);
    // layer 3
    gather_bf16_kernel<<<gatherGrid, 256, 0, stream>>>(xb0, row_ptr, csr, aggb, N);
    gemm_mfma<<<gemmGrid, 256, 0, stream>>>(aggb, xb0, Wp3, b3, xb1, N);
    // head
    head_kernel<<<(N + 255) / 256, 256, 0, stream>>>(xb1, Wlin, blin, (float*)d_out, N);
}

// Round 6
// 549.060 us; speedup vs baseline: 2.0659x; 1.1017x over previous
//
#include <hip/hip_runtime.h>
#include <hip/hip_bf16.h>
#include <math.h>

#define C128 128
#define OUT_CH 10

typedef __attribute__((ext_vector_type(8))) short short8;
typedef __attribute__((ext_vector_type(8))) unsigned short ushort8v;
typedef __attribute__((ext_vector_type(4))) float f32x4;

__device__ __forceinline__ unsigned short f2bf(float f) {
    unsigned b = __float_as_uint(f);
    unsigned r = (b + 0x7FFF + ((b >> 16) & 1)) >> 16;   // RNE
    return (unsigned short)r;
}
__device__ __forceinline__ float bf2f(unsigned short u) {
    return __uint_as_float(((unsigned)u) << 16);
}

// ---------------- CSR build ----------------
// XCD partitioning: blocks come in groups of 8 (round-robin across XCDs);
// block with (blockIdx&7)==p only touches dsts with ((dst>>11)&7)==p, so each
// cursor/csr cache line is written by exactly one XCD -> write-back once.

__global__ void hist_kernel(const int* __restrict__ ei, int* __restrict__ deg, int E) {
    int p = blockIdx.x & 7;
    int e = (blockIdx.x >> 3) * blockDim.x + threadIdx.x;
    if (e < E) {
        int dst = ei[E + e];
        if (((dst >> 11) & 7) == p) atomicAdd(&deg[dst], 1);
    }
}

__global__ __launch_bounds__(256) void tile_sum_kernel(const int* __restrict__ deg,
                                                       int* __restrict__ tile_sums, int N) {
    __shared__ int red[256];
    int t = threadIdx.x;
    int i = blockIdx.x * 256 + t;
    red[t] = (i < N) ? deg[i] : 0;
    __syncthreads();
    for (int off = 128; off > 0; off >>= 1) {
        if (t < off) red[t] += red[t + off];
        __syncthreads();
    }
    if (t == 0) tile_sums[blockIdx.x] = red[0];
}

__global__ __launch_bounds__(512) void tile_scan_kernel(const int* __restrict__ tile_sums,
                                                        int* __restrict__ tile_off, int numTiles) {
    __shared__ int s[512];
    int t = threadIdx.x;
    int v = (t < numTiles) ? tile_sums[t] : 0;
    s[t] = v;
    __syncthreads();
    for (int off = 1; off < 512; off <<= 1) {
        int u = (t >= off) ? s[t - off] : 0;
        __syncthreads();
        s[t] += u;
        __syncthreads();
    }
    if (t < numTiles) tile_off[t] = s[t] - v;
}

// per-tile exclusive scan + offset -> row_ptr; also overwrites deg[] to serve
// as fill's cursor (each element read once by its own thread before overwrite).
__global__ __launch_bounds__(256) void scan_emit_kernel(int* __restrict__ deg_cursor,
                                                        const int* __restrict__ tile_off,
                                                        int* __restrict__ row_ptr, int N, int E) {
    __shared__ int s[256];
    int t = threadIdx.x;
    int i = blockIdx.x * 256 + t;
    int v = (i < N) ? deg_cursor[i] : 0;
    s[t] = v;
    __syncthreads();
    for (int off = 1; off < 256; off <<= 1) {
        int u = (t >= off) ? s[t - off] : 0;
        __syncthreads();
        s[t] += u;
        __syncthreads();
    }
    if (i < N) {
        int o = tile_off[blockIdx.x] + s[t] - v;
        row_ptr[i] = o;
        deg_cursor[i] = o;
    }
    if (blockIdx.x == 0 && t == 0) row_ptr[N] = E;
}

__global__ void fill_kernel(const int* __restrict__ ei, const float* __restrict__ ew,
                            int* __restrict__ cursor, int2* __restrict__ csr, int E) {
    int p = blockIdx.x & 7;
    int e = (blockIdx.x >> 3) * blockDim.x + threadIdx.x;
    if (e < E) {
        int dst = ei[E + e];
        if (((dst >> 11) & 7) == p) {
            int pos = atomicAdd(&cursor[dst], 1);
            csr[pos] = make_int2(ei[e], __float_as_int(ew[e]));
        }
    }
}

// ---------------- fp32 -> bf16 conversion (layer-1 input) ----------------

__global__ __launch_bounds__(256) void cvt_bf16_kernel(const float4* __restrict__ x,
                                                       ushort4* __restrict__ xb, int n4) {
    int i = blockIdx.x * blockDim.x + threadIdx.x;
    if (i < n4) {
        float4 v = x[i];
        ushort4 o;
        o.x = f2bf(v.x); o.y = f2bf(v.y); o.z = f2bf(v.z); o.w = f2bf(v.w);
        xb[i] = o;
    }
}

// ---------------- weight pack: [Wr;Wt] (256x128 fp32) -> MFMA B-frag order bf16 ----------------

__global__ __launch_bounds__(256) void pack_w_kernel(const float* __restrict__ Wr,
                                                     const float* __restrict__ Wt,
                                                     unsigned short* __restrict__ Wp) {
    int idx = blockIdx.x * 256 + threadIdx.x;     // 32768
    int j    = idx & 7;
    int n    = (idx >> 3) & 127;
    int quad = (idx >> 10) & 3;
    int ks   = idx >> 12;
    const float* W = (ks < 4) ? Wr : Wt;
    int k = (ks & 3) * 32 + quad * 8 + j;
    Wp[idx] = f2bf(W[(size_t)k * C128 + n]);
}

// ---------------- aggregation: one wave per node, 4 edges/iter, 2x unrolled ----------------

__global__ __launch_bounds__(256) void gather_bf16_kernel(
    const unsigned short* __restrict__ xb, const int* __restrict__ row_ptr,
    const int2* __restrict__ csr, unsigned short* __restrict__ aggb, int N)
{
    int node = blockIdx.x * 4 + (threadIdx.x >> 6);
    if (node >= N) return;
    int lane = threadIdx.x & 63;
    int g   = lane >> 4;        // edge group 0..3
    int l16 = lane & 15;        // channel group (8 bf16 = 16 B)
    int i  = row_ptr[node] + g;
    int e1 = row_ptr[node + 1];
    float acc[8];
#pragma unroll
    for (int j = 0; j < 8; ++j) acc[j] = 0.f;
    // 2x unrolled: two independent 16B row loads in flight
    for (; i + 4 < e1; i += 8) {
        int2 r0 = csr[i];
        int2 r1 = csr[i + 4];
        float w0 = __int_as_float(r0.y);
        float w1 = __int_as_float(r1.y);
        ushort8v raw0 = *(const ushort8v*)&xb[(size_t)r0.x * C128 + l16 * 8];
        ushort8v raw1 = *(const ushort8v*)&xb[(size_t)r1.x * C128 + l16 * 8];
#pragma unroll
        for (int j = 0; j < 8; ++j) acc[j] += bf2f(raw0[j]) * w0;
#pragma unroll
        for (int j = 0; j < 8; ++j) acc[j] += bf2f(raw1[j]) * w1;
    }
    if (i < e1) {
        int2 rec = csr[i];
        float w = __int_as_float(rec.y);
        ushort8v raw = *(const ushort8v*)&xb[(size_t)rec.x * C128 + l16 * 8];
#pragma unroll
        for (int j = 0; j < 8; ++j) acc[j] += bf2f(raw[j]) * w;
    }
#pragma unroll
    for (int j = 0; j < 8; ++j) {
        acc[j] += __shfl_xor(acc[j], 16, 64);
        acc[j] += __shfl_xor(acc[j], 32, 64);
    }
    if (g == 0) {
        ushort8v o;
#pragma unroll
        for (int j = 0; j < 8; ++j) o[j] = f2bf(acc[j]);
        *(ushort8v*)&aggb[(size_t)node * C128 + l16 * 8] = o;
    }
}

// ---------------- MFMA dual GEMM: out = relu([aggb|xb] @ [Wr;Wt] + b), bf16 out ----------------

#define A_STRIDE 40   // bf16 elements per staged row (32 data + 8 pad)

__global__ __launch_bounds__(256) void gemm_mfma(
    const unsigned short* __restrict__ aggb, const unsigned short* __restrict__ xb,
    const unsigned short* __restrict__ Wp, const float* __restrict__ bias,
    unsigned short* __restrict__ outb, int N)
{
    __shared__ unsigned short WL[8 * 4 * 128 * 8];   // 64 KB, full packed weights
    __shared__ unsigned short AL[64 * A_STRIDE];     // 5 KB, one 64x32 A chunk

    const int t = threadIdx.x;
    const int node0 = blockIdx.x * 64;
    const int w    = t >> 6;
    const int lane = t & 63;
    const int l15  = lane & 15;
    const int quad = lane >> 4;

#pragma unroll
    for (int i = 0; i < 16; ++i) {
        int slot = i * 256 + t;
        *(uint4*)&WL[slot * 8] = *(const uint4*)&Wp[slot * 8];
    }

    float bv[8];
#pragma unroll
    for (int nt = 0; nt < 8; ++nt) bv[nt] = bias[nt * 16 + l15];

    f32x4 acc[8];
#pragma unroll
    for (int nt = 0; nt < 8; ++nt) acc[nt] = (f32x4){0.f, 0.f, 0.f, 0.f};

    const int sr = t >> 2;        // 0..63
    const int sc = t & 3;         // 0..3
    const int srow = node0 + sr;

    for (int ks = 0; ks < 8; ++ks) {
        const unsigned short* Asrc = (ks < 4) ? aggb : xb;
        const int koff = (ks & 3) * 32;
        __syncthreads();
        uint4 av = make_uint4(0u, 0u, 0u, 0u);
        if (srow < N) av = *(const uint4*)&Asrc[(size_t)srow * C128 + koff + sc * 8];
        *(uint4*)&AL[sr * A_STRIDE + sc * 8] = av;
        __syncthreads();

        short8 a = *(const short8*)&AL[(w * 16 + l15) * A_STRIDE + quad * 8];
#pragma unroll
        for (int nt = 0; nt < 8; ++nt) {
            short8 b = *(const short8*)&WL[(((ks * 4 + quad) * 128) + nt * 16 + l15) * 8];
            acc[nt] = __builtin_amdgcn_mfma_f32_16x16x32_bf16(a, b, acc[nt], 0, 0, 0);
        }
    }

#pragma unroll
    for (int r = 0; r < 4; ++r) {
        int row = node0 + w * 16 + quad * 4 + r;
        if (row < N) {
#pragma unroll
            for (int nt = 0; nt < 8; ++nt) {
                float v = fmaxf(acc[nt][r] + bv[nt], 0.f);
                outb[(size_t)row * C128 + nt * 16 + l15] = f2bf(v);
            }
        }
    }
}

// ---------------- head: bf16 x3 @ W_lin + b_lin, log_softmax ----------------

__global__ __launch_bounds__(256) void head_kernel(
    const unsigned short* __restrict__ x, const float* __restrict__ Wl,
    const float* __restrict__ bl, float* __restrict__ out, int N)
{
    int n = blockIdx.x * blockDim.x + threadIdx.x;
    if (n >= N) return;
    float acc[OUT_CH];
#pragma unroll
    for (int c = 0; c < OUT_CH; ++c) acc[c] = bl[c];
    const ushort4* row = (const ushort4*)(x + (size_t)n * C128);
#pragma unroll 4
    for (int kk = 0; kk < 32; ++kk) {
        ushort4 u = row[kk];
        float vx = bf2f(u.x), vy = bf2f(u.y), vz = bf2f(u.z), vw = bf2f(u.w);
        int k = kk * 4;
#pragma unroll
        for (int c = 0; c < OUT_CH; ++c) {
            acc[c] += vx * Wl[(k + 0) * OUT_CH + c]
                    + vy * Wl[(k + 1) * OUT_CH + c]
                    + vz * Wl[(k + 2) * OUT_CH + c]
                    + vw * Wl[(k + 3) * OUT_CH + c];
        }
    }
    float m = acc[0];
#pragma unroll
    for (int c = 1; c < OUT_CH; ++c) m = fmaxf(m, acc[c]);
    float s = 0.f;
#pragma unroll
    for (int c = 0; c < OUT_CH; ++c) s += __expf(acc[c] - m);
    float lse = m + __logf(s);
#pragma unroll
    for (int c = 0; c < OUT_CH; ++c) out[(size_t)n * OUT_CH + c] = acc[c] - lse;
}

// ---------------- launch ----------------

extern "C" void kernel_launch(void* const* d_in, const int* in_sizes, int n_in,
                              void* d_out, int out_size, void* d_ws, size_t ws_size,
                              hipStream_t stream) {
    const float* x0   = (const float*)d_in[0];
    const int*   ei   = (const int*)  d_in[1];
    const float* ew   = (const float*)d_in[2];
    const float* W1r  = (const float*)d_in[3];
    const float* b1   = (const float*)d_in[4];
    const float* W1t  = (const float*)d_in[5];
    const float* W2r  = (const float*)d_in[6];
    const float* b2   = (const float*)d_in[7];
    const float* W2t  = (const float*)d_in[8];
    const float* W3r  = (const float*)d_in[9];
    const float* b3   = (const float*)d_in[10];
    const float* W3t  = (const float*)d_in[11];
    const float* Wlin = (const float*)d_in[12];
    const float* blin = (const float*)d_in[13];

    const int N = in_sizes[0] / C128;
    const int E = in_sizes[1] / 2;
    const int numTiles = (N + 255) / 256;

    char* ws = (char*)d_ws;
    size_t bb = (size_t)N * C128 * sizeof(unsigned short);   // 25.6 MB
    unsigned short* aggb = (unsigned short*)(ws);
    unsigned short* xb0  = (unsigned short*)(ws + bb);
    unsigned short* xb1  = (unsigned short*)(ws + 2 * bb);
    unsigned short* Wp1  = (unsigned short*)(ws + 3 * bb);   // 3 x 32768 ushorts
    unsigned short* Wp2  = Wp1 + 32768;
    unsigned short* Wp3  = Wp2 + 32768;
    int2*  csr     = (int2*)(ws + 3 * bb + 3 * 32768 * sizeof(unsigned short));
    int*   row_ptr = (int*)(csr + E);
    int*   cursor  = row_ptr + (N + 1);       // deg histogram, then fill cursor
    int*   tile_sums = cursor + N;
    int*   tile_off  = tile_sums + 512;

    const int edgeBlocks = (E + 255) / 256;

    // build CSR (dst-indexed), once per call
    hipMemsetAsync(cursor, 0, (size_t)N * sizeof(int), stream);
    hist_kernel<<<edgeBlocks * 8, 256, 0, stream>>>(ei, cursor, E);
    tile_sum_kernel<<<numTiles, 256, 0, stream>>>(cursor, tile_sums, N);
    tile_scan_kernel<<<1, 512, 0, stream>>>(tile_sums, tile_off, numTiles);
    scan_emit_kernel<<<numTiles, 256, 0, stream>>>(cursor, tile_off, row_ptr, N, E);
    fill_kernel<<<edgeBlocks * 8, 256, 0, stream>>>(ei, ew, cursor, csr, E);

    // bf16 input + packed weights
    cvt_bf16_kernel<<<(N * C128 / 4 + 255) / 256, 256, 0, stream>>>(
        (const float4*)x0, (ushort4*)xb0, N * C128 / 4);
    pack_w_kernel<<<128, 256, 0, stream>>>(W1r, W1t, Wp1);
    pack_w_kernel<<<128, 256, 0, stream>>>(W2r, W2t, Wp2);
    pack_w_kernel<<<128, 256, 0, stream>>>(W3r, W3t, Wp3);

    int gatherGrid = (N + 3) / 4;
    int gemmGrid   = (N + 63) / 64;

    // layer 1
    gather_bf16_kernel<<<gatherGrid, 256, 0, stream>>>(xb0, row_ptr, csr, aggb, N);
    gemm_mfma<<<gemmGrid, 256, 0, stream>>>(aggb, xb0, Wp1, b1, xb1, N);
    // layer 2
    gather_bf16_kernel<<<gatherGrid, 256, 0, stream>>>(xb1, row_ptr, csr, aggb, N);
    gemm_mfma<<<gemmGrid, 256, 0, stream>>>(aggb, xb1, Wp2, b2, xb0, N);
    // layer 3
    gather_bf16_kernel<<<gatherGrid, 256, 0, stream>>>(xb0, row_ptr, csr, aggb, N);
    gemm_mfma<<<gemmGrid, 256, 0, stream>>>(aggb, xb0, Wp3, b3, xb1, N);
    // head
    head_kernel<<<(N + 255) / 256, 256, 0, stream>>>(xb1, Wlin, blin, (float*)d_out, N);
}